// Round 14
// baseline (269.824 us; speedup 1.0000x reference)
//
#include <hip/hip_runtime.h>
#include <hip/hip_fp16.h>

#define SEQ 256
#define NPOS 1024

typedef __attribute__((ext_vector_type(8))) short bf16x8;
typedef __attribute__((ext_vector_type(4))) float f32x4;

__device__ __forceinline__ unsigned short f2bf(float x) {
  unsigned int u = __float_as_uint(x);
  return (unsigned short)((u + 0x7FFFu + ((u >> 16) & 1u)) >> 16);
}

// DPP cross-lane add helpers (VALU pipe)
template <int CTRL>
__device__ __forceinline__ float dpp_add(float x) {
  return x + __int_as_float(__builtin_amdgcn_update_dpp(
                 0, __float_as_int(x), CTRL, 0xF, 0xF, true));
}
#define DPP_XOR1 0xB1
#define DPP_XOR2 0x4E
#define DPP_ROR4 0x124
#define DPP_ROR8 0x128
__device__ __forceinline__ float swz_xor16(float x) {
  return __int_as_float(__builtin_amdgcn_ds_swizzle(__float_as_int(x), 0x401F));
}
__device__ __forceinline__ float bperm(int addr, float x) {
  return __int_as_float(__builtin_amdgcn_ds_bpermute(addr, __float_as_int(x)));
}

// ---------------- prep: squash + LN -> emb0 (fp32) + emb0b (bf16)
__global__ __launch_bounds__(256) void prep_kernel(
    const float* __restrict__ x, const float* __restrict__ g,
    const float* __restrict__ be, float* __restrict__ emb0,
    unsigned short* __restrict__ emb0b) {
  const int pos = blockIdx.x;
  const int t = threadIdx.x;
  float v = x[(size_t)pos * 256 + t];
  float sn = v * v;
  sn += __shfl_xor(sn, 1); sn += __shfl_xor(sn, 2);
  sn += __shfl_xor(sn, 4); sn += __shfl_xor(sn, 8);
  float e = v * (sn / (1.f + sn)) * rsqrtf(sn + 1e-9f);
  __shared__ float red[2][4];
  float s1 = e, s2 = e * e;
  for (int m = 1; m < 64; m <<= 1) { s1 += __shfl_xor(s1, m); s2 += __shfl_xor(s2, m); }
  if ((t & 63) == 0) { red[0][t >> 6] = s1; red[1][t >> 6] = s2; }
  __syncthreads();
  float tot = 0.f, tot2 = 0.f;
#pragma unroll
  for (int i = 0; i < 4; i++) { tot += red[0][i]; tot2 += red[1][i]; }
  float mean = tot * (1.f / 256.f);
  float var = tot2 * (1.f / 256.f) - mean * mean;
  float val = g[t] * (e - mean) * rsqrtf(var + 1e-3f) + be[t];
  emb0[(size_t)pos * 256 + t] = val;
  emb0b[(size_t)pos * 256 + t] = f2bf(val);
}

// ---------------- Bt builder: Bt[od][k] = W[(w*IN_H+h)][od*16+l], k=w*ESTR+h*16+l
template <int K, int ESTR, int IN_H>
__global__ __launch_bounds__(256) void conv_bt(
    const float* __restrict__ W, unsigned short* __restrict__ Bt) {
  int idx = blockIdx.x * 256 + threadIdx.x;
  if (idx >= 512 * K) return;
  int od = idx / K, k = idx - od * K;
  int w = k / ESTR, hl = k - w * ESTR;
  int h = hl >> 4, l = hl & 15;
  Bt[idx] = f2bf(W[(size_t)(w * IN_H + h) * 8192 + od * 16 + l]);
}

// ---------------- bias sum: bias[od] = sum_i Bi[i][od]
template <int INH>
__global__ __launch_bounds__(512) void bias_sum(
    const float* __restrict__ Bi, float* __restrict__ bias) {
  const int t = threadIdx.x;
  float s = 0.f;
  for (int i = 0; i < INH; i++) s += Bi[(size_t)i * 512 + t];
  bias[t] = s;
}

// ---------------- sa_gemm: sA[p][od] = sum_k A[p][k]*Bt[od][k] + bias[od]
// A[p][k] = embB[p+w-2][c] (k=w*ESTR+c, zero-padded at seq edges).
// MFMA 16x16x32 bf16; block = 32 p x 64 od (4 waves x 16 od x 2 p-subtiles).
template <int K, int ESTR>
__global__ __launch_bounds__(256) void sa_gemm(
    const unsigned short* __restrict__ embB, const unsigned short* __restrict__ Bt,
    const float* __restrict__ bias, float* __restrict__ sA) {
  const int pt = blockIdx.x;      // 32 positions per tile
  const int og = blockIdx.y;      // 8 od-groups of 64
  const int t = threadIdx.x;      // 256
  const int wv = t >> 6, l = t & 63;
  const int od0 = og * 64 + wv * 16;
  __shared__ unsigned short A_lds[32][40];  // rows padded to 80B (16B-aligned)
  f32x4 acc0 = {0.f, 0.f, 0.f, 0.f};
  f32x4 acc1 = {0.f, 0.f, 0.f, 0.f};
  for (int kc = 0; kc < K / 32; ++kc) {
    const int k0 = kc * 32;
    // stage A tile 32x32: 1024 elems / 256 threads
#pragma unroll
    for (int j = 0; j < 4; ++j) {
      int idx = t + j * 256;
      int pm = idx >> 5, kk = idx & 31;
      int k = k0 + kk;
      int w = k / ESTR, c = k - w * ESTR;
      int pg = pt * 32 + pm;
      int s = (pg & 255) + w - 2;
      unsigned short val = 0;
      if (s >= 0 && s < SEQ) val = embB[(size_t)(pg + w - 2) * ESTR + c];
      A_lds[pm][kk] = val;
    }
    __syncthreads();
    bf16x8 bfr = *(const bf16x8*)(Bt + (size_t)(od0 + (l & 15)) * K + k0 + (l >> 4) * 8);
    bf16x8 af0 = *(const bf16x8*)&A_lds[(l & 15)][(l >> 4) * 8];
    bf16x8 af1 = *(const bf16x8*)&A_lds[16 + (l & 15)][(l >> 4) * 8];
    acc0 = __builtin_amdgcn_mfma_f32_16x16x32_bf16(af0, bfr, acc0, 0, 0, 0);
    acc1 = __builtin_amdgcn_mfma_f32_16x16x32_bf16(af1, bfr, acc1, 0, 0, 0);
    __syncthreads();
  }
  const int col = l & 15;
  const float bs = bias[od0 + col];
#pragma unroll
  for (int j = 0; j < 4; ++j) {
    int row = (l >> 4) * 4 + j;
    sA[(size_t)(pt * 32 + row) * 512 + od0 + col] = acc0[j] + bs;
    sA[(size_t)(pt * 32 + 16 + row) * 512 + od0 + col] = acc1[j] + bs;
  }
}

// ---------------- einsum (r12 PT=64 version, half2 stores)
template <int INH, int IN_H, int ESTR>
__global__ __launch_bounds__(512) void einsum_kernel(
    const float* __restrict__ W, const float* __restrict__ Bi,
    const float* __restrict__ emb, __half* __restrict__ u, int pos0) {
  constexpr int PT = 64;
  const int i = blockIdx.x;
  const int pt = blockIdx.y;
  const int t = threadIdx.x;
  const int c = t & 255;
  const int ph = t >> 8;
  const int w = i / IN_H, h = i % IN_H;
  __shared__ float W_lds[16][512];
  __shared__ float we_lds[PT][16];
  const float* Wi = W + (size_t)i * 8192;
#pragma unroll
  for (int j = 0; j < 4; j++) {
    const float4 wv = *(const float4*)(Wi + (size_t)t * 16 + j * 4);
    W_lds[j * 4 + 0][t] = wv.x; W_lds[j * 4 + 1][t] = wv.y;
    W_lds[j * 4 + 2][t] = wv.z; W_lds[j * 4 + 3][t] = wv.w;
  }
#pragma unroll
  for (int j = 0; j < PT * 16 / 512; j++) {
    int idx = t + j * 512;
    int p = idx >> 4, l = idx & 15;
    int pos = pos0 + pt * PT + p;
    int s = pos & 255;
    int sr = s + w - 2;
    float val = 0.f;
    if (sr >= 0 && sr < SEQ) val = emb[(size_t)(pos + (w - 2)) * ESTR + h * 16 + l];
    we_lds[p][l] = val;
  }
  __syncthreads();
  float wr0[16], wr1[16];
#pragma unroll
  for (int l = 0; l < 16; l++) { wr0[l] = W_lds[l][2 * c]; wr1[l] = W_lds[l][2 * c + 1]; }
  const float b0 = Bi[(size_t)i * 512 + 2 * c];
  const float b1 = Bi[(size_t)i * 512 + 2 * c + 1];
  __half* ub = u + ((size_t)(pt * PT + ph * 32) * INH + i) * 512 + 2 * c;
#pragma unroll 4
  for (int p2 = 0; p2 < 32; p2++) {
    const int p = ph * 32 + p2;
    float a0 = b0, a1 = b1;
#pragma unroll
    for (int l = 0; l < 16; l++) {
      float e = we_lds[p][l];
      a0 = fmaf(wr0[l], e, a0);
      a1 = fmaf(wr1[l], e, a1);
    }
    *(__half2*)(ub + (size_t)p2 * INH * 512) = __floats2half2_rn(a0, a1);
  }
}

// ---------------- routing: pass A READ ELIMINATED (precomputed sA via MFMA
// GEMM; v1 only feeds softmax logits so bf16-grade sA is safe). u_hat now
// streamed only 2x (passes B,C). DPP softmax; VGPR<=64 class.
template <int INH, bool MASK, bool FINAL>
__global__ __launch_bounds__(512) void route_kernel(
    const __half* __restrict__ u, const float* __restrict__ sA,
    const float* __restrict__ g, const float* __restrict__ be,
    const float* __restrict__ g_o, const float* __restrict__ b_o,
    float* __restrict__ outp, unsigned short* __restrict__ outb, int pos0) {
  constexpr int ROWS = INH / 8;
  const int w = threadIdx.x >> 6;
  const int l = threadIdx.x & 63;
  const int o = l >> 1;
  const int p = blockIdx.x;
  const int posg = pos0 + p;
  const int xaddr = ((l ^ 32) << 2);
  const __half* ug = u + (size_t)p * INH * 512 + (size_t)w * ROWS * 512 + l * 8;

  __shared__ float red_s[8][512];

#define UNPACK(q, f)                                            \
  {                                                             \
    float2 f0 = __half22float2(*(const __half2*)&(q).x);        \
    float2 f1 = __half22float2(*(const __half2*)&(q).y);        \
    float2 f2 = __half22float2(*(const __half2*)&(q).z);        \
    float2 f3 = __half22float2(*(const __half2*)&(q).w);        \
    f[0] = f0.x; f[1] = f0.y; f[2] = f1.x; f[3] = f1.y;         \
    f[4] = f2.x; f[5] = f2.y; f[6] = f3.x; f[7] = f3.y;         \
  }

  // ---- iter 1 from precomputed sA (2KB/position, L2-hot)
  float s8[8];
  {
    const float* sp = sA + (size_t)posg * 512 + l * 8;
    float4 a = *(const float4*)sp;
    float4 b = *(const float4*)(sp + 4);
    s8[0] = a.x; s8[1] = a.y; s8[2] = a.z; s8[3] = a.w;
    s8[4] = b.x; s8[5] = b.y; s8[6] = b.z; s8[7] = b.w;
  }
  const float c1 = MASK ? (o == 0 ? 0.f : (1.f / 31.f)) : (1.f / 32.f);
  float vd[8], vout[8];
  {
    float sn = 0.f;
#pragma unroll
    for (int k = 0; k < 8; k++) { s8[k] *= c1; sn += s8[k] * s8[k]; }
    sn = dpp_add<DPP_XOR1>(sn);
    float f = (sn / (1.f + sn)) * rsqrtf(sn + 1e-9f);
#pragma unroll
    for (int k = 0; k < 8; k++) vd[k] = s8[k] * f;  // vd = v1
  }

  // ---- passes B, C (iters 2, 3); pass C dots against v1+v2 (b telescopes)
#pragma unroll
  for (int iter = 0; iter < 2; iter++) {
    float sacc[8];
#pragma unroll
    for (int k = 0; k < 8; k++) sacc[k] = 0.f;
#pragma unroll 2
    for (int r = 0; r < ROWS; r++) {
      uint4 q = *(const uint4*)(ug + (size_t)r * 512);
      float u8[8];
      UNPACK(q, u8);
      float a = u8[0] * vd[0];
#pragma unroll
      for (int k = 1; k < 8; k++) a = fmaf(u8[k], vd[k], a);
      a = dpp_add<DPP_XOR1>(a);
      float e = (MASK && o == 0) ? 0.f : __expf(a);
      float ss = dpp_add<DPP_XOR1>(e);
      ss = dpp_add<DPP_XOR2>(ss);
      ss = dpp_add<DPP_ROR4>(ss);
      ss = dpp_add<DPP_ROR8>(ss);
      ss += swz_xor16(ss);
      ss += bperm(xaddr, ss);
      float c = __fdividef(e + e, ss);
#pragma unroll
      for (int k = 0; k < 8; k++) sacc[k] = fmaf(c, u8[k], sacc[k]);
    }
    __syncthreads();
    *(float4*)&red_s[w][l * 8]     = make_float4(sacc[0], sacc[1], sacc[2], sacc[3]);
    *(float4*)&red_s[w][l * 8 + 4] = make_float4(sacc[4], sacc[5], sacc[6], sacc[7]);
    __syncthreads();
#pragma unroll
    for (int k = 0; k < 8; k++) sacc[k] = 0.f;
#pragma unroll
    for (int w2 = 0; w2 < 8; w2++) {
      float4 a = *(const float4*)&red_s[w2][l * 8];
      float4 b = *(const float4*)&red_s[w2][l * 8 + 4];
      sacc[0] += a.x; sacc[1] += a.y; sacc[2] += a.z; sacc[3] += a.w;
      sacc[4] += b.x; sacc[5] += b.y; sacc[6] += b.z; sacc[7] += b.w;
    }
    float sn = 0.f;
#pragma unroll
    for (int k = 0; k < 8; k++) sn += sacc[k] * sacc[k];
    sn = dpp_add<DPP_XOR1>(sn);
    float f = (sn / (1.f + sn)) * rsqrtf(sn + 1e-9f);
#pragma unroll
    for (int k = 0; k < 8; k++) {
      vout[k] = sacc[k] * f;
      vd[k] += vout[k];
    }
  }

  // ---- epilogue: LN over 512
  float s1 = 0.f, s2 = 0.f;
#pragma unroll
  for (int k = 0; k < 8; k++) { s1 += vout[k]; s2 += vout[k] * vout[k]; }
  for (int m = 1; m < 64; m <<= 1) { s1 += __shfl_xor(s1, m); s2 += __shfl_xor(s2, m); }
  float mean = s1 * (1.f / 512.f);
  float var = s2 * (1.f / 512.f) - mean * mean;
  float rstd = rsqrtf(var + 1e-3f);
  const float4 g0 = *(const float4*)(g + 8 * l);
  const float4 g1 = *(const float4*)(g + 8 * l + 4);
  const float4 be0 = *(const float4*)(be + 8 * l);
  const float4 be1 = *(const float4*)(be + 8 * l + 4);
  float nv[8];
  nv[0] = g0.x * (vout[0] - mean) * rstd + be0.x;
  nv[1] = g0.y * (vout[1] - mean) * rstd + be0.y;
  nv[2] = g0.z * (vout[2] - mean) * rstd + be0.z;
  nv[3] = g0.w * (vout[3] - mean) * rstd + be0.w;
  nv[4] = g1.x * (vout[4] - mean) * rstd + be1.x;
  nv[5] = g1.y * (vout[5] - mean) * rstd + be1.y;
  nv[6] = g1.z * (vout[6] - mean) * rstd + be1.z;
  nv[7] = g1.w * (vout[7] - mean) * rstd + be1.w;

  if (!FINAL) {
    if (w == 0) {
      float4 w0 = {nv[0], nv[1], nv[2], nv[3]};
      float4 w1 = {nv[4], nv[5], nv[6], nv[7]};
      float* op = outp + (size_t)posg * 512 + 8 * l;
      *(float4*)op = w0; *(float4*)(op + 4) = w1;
      uint4 bb;
      bb.x = (unsigned)f2bf(nv[0]) | ((unsigned)f2bf(nv[1]) << 16);
      bb.y = (unsigned)f2bf(nv[2]) | ((unsigned)f2bf(nv[3]) << 16);
      bb.z = (unsigned)f2bf(nv[4]) | ((unsigned)f2bf(nv[5]) << 16);
      bb.w = (unsigned)f2bf(nv[6]) | ((unsigned)f2bf(nv[7]) << 16);
      *(uint4*)(outb + (size_t)posg * 512 + 8 * l) = bb;
    }
  } else {
    float l2 = 0.f;
#pragma unroll
    for (int k = 0; k < 8; k++) l2 += nv[k] * nv[k];
    l2 = dpp_add<DPP_XOR1>(l2);
    float len = sqrtf(l2 + 1e-9f);
    float a1 = len, a2 = len * len;
    for (int m = 1; m < 64; m <<= 1) { a1 += __shfl_xor(a1, m); a2 += __shfl_xor(a2, m); }
    float mm = a1 * (1.f / 64.f);
    float vv = a2 * (1.f / 64.f) - mm * mm;
    if (w == 0 && (l & 1) == 0)
      outp[(size_t)posg * 32 + o] = g_o[o] * (len - mm) * rsqrtf(vv + 1e-3f) + b_o[o];
  }
#undef UNPACK
}

extern "C" void kernel_launch(void* const* d_in, const int* in_sizes, int n_in,
                              void* d_out, int out_size, void* d_ws, size_t ws_size,
                              hipStream_t stream) {
  const float* x    = (const float*)d_in[0];
  const float* W0   = (const float*)d_in[1];
  const float* B0   = (const float*)d_in[2];
  const float* W1   = (const float*)d_in[3];
  const float* B1   = (const float*)d_in[4];
  const float* g_i  = (const float*)d_in[5];
  const float* b_i  = (const float*)d_in[6];
  const float* g_m0 = (const float*)d_in[7];
  const float* b_m0 = (const float*)d_in[8];
  const float* g_m1 = (const float*)d_in[9];
  const float* b_m1 = (const float*)d_in[10];
  const float* g_o  = (const float*)d_in[11];
  const float* b_o  = (const float*)d_in[12];
  float* out = (float*)d_out;

  char* ws = (char*)d_ws;
  float* emb0            = (float*)(ws);                      // 1 MB
  float* emb1            = (float*)(ws + 1048576);            // 2 MB
  unsigned short* emb0b  = (unsigned short*)(ws + 3145728);   // 0.5 MB
  unsigned short* emb1b  = (unsigned short*)(ws + 3670016);   // 1 MB
  float* sA0             = (float*)(ws + 4718592);            // 2 MB
  float* sA1             = (float*)(ws + 6815744);            // 2 MB
  unsigned short* Bt0    = (unsigned short*)(ws + 8912896);   // 1.25 MB
  unsigned short* Bt1    = (unsigned short*)(ws + 10223616);  // 2.5 MB
  float* bias0           = (float*)(ws + 12845056);           // 2 KB
  float* bias1           = (float*)(ws + 12849152);           // 2 KB
  __half* ubuf           = (__half*)(ws + 13107200);

  size_t avail = ws_size > (size_t)13107200 ? ws_size - 13107200 : 0;
  int chunk = 1024;
  while (chunk > 128 && (size_t)chunk * 163840 > avail) chunk >>= 1;

  prep_kernel<<<NPOS, 256, 0, stream>>>(x, g_i, b_i, emb0, emb0b);
  conv_bt<1280, 256, 16><<<(512 * 1280 + 255) / 256, 256, 0, stream>>>(W0, Bt0);
  conv_bt<2560, 512, 32><<<(512 * 2560 + 255) / 256, 256, 0, stream>>>(W1, Bt1);
  bias_sum<80><<<1, 512, 0, stream>>>(B0, bias0);
  bias_sum<160><<<1, 512, 0, stream>>>(B1, bias1);
  sa_gemm<1280, 256><<<dim3(32, 8), 256, 0, stream>>>(emb0b, Bt0, bias0, sA0);

  for (int p0 = 0; p0 < NPOS; p0 += chunk) {
    int cp = (NPOS - p0 < chunk) ? (NPOS - p0) : chunk;
    einsum_kernel<80, 16, 256><<<dim3(80, cp / 64), 512, 0, stream>>>(W0, B0, emb0, ubuf, p0);
    route_kernel<80, false, false><<<cp, 512, 0, stream>>>(ubuf, sA0, g_m0, b_m0, nullptr, nullptr, emb1, emb1b, p0);
  }

  sa_gemm<2560, 512><<<dim3(32, 8), 256, 0, stream>>>(emb1b, Bt1, bias1, sA1);

  for (int p0 = 0; p0 < NPOS; p0 += chunk) {
    int cp = (NPOS - p0 < chunk) ? (NPOS - p0) : chunk;
    einsum_kernel<160, 32, 512><<<dim3(160, cp / 64), 512, 0, stream>>>(W1, B1, emb1, ubuf, p0);
    route_kernel<160, true, true><<<cp, 512, 0, stream>>>(ubuf, sA1, g_m1, b_m1, g_o, b_o, out, nullptr, p0);
  }
}

// Round 15
// 232.501 us; speedup vs baseline: 1.1605x; 1.1605x over previous
//
#include <hip/hip_runtime.h>
#include <hip/hip_fp16.h>

#define SEQ 256
#define NPOS 1024

typedef __attribute__((ext_vector_type(8))) short bf16x8;
typedef __attribute__((ext_vector_type(4))) float f32x4;

__device__ __forceinline__ unsigned short f2bf(float x) {
  unsigned int u = __float_as_uint(x);
  return (unsigned short)((u + 0x7FFFu + ((u >> 16) & 1u)) >> 16);
}

// DPP cross-lane add helpers (VALU pipe)
template <int CTRL>
__device__ __forceinline__ float dpp_add(float x) {
  return x + __int_as_float(__builtin_amdgcn_update_dpp(
                 0, __float_as_int(x), CTRL, 0xF, 0xF, true));
}
#define DPP_XOR1 0xB1
#define DPP_XOR2 0x4E
#define DPP_ROR4 0x124
#define DPP_ROR8 0x128
__device__ __forceinline__ float swz_xor16(float x) {
  return __int_as_float(__builtin_amdgcn_ds_swizzle(__float_as_int(x), 0x401F));
}
__device__ __forceinline__ float bperm(int addr, float x) {
  return __int_as_float(__builtin_amdgcn_ds_bpermute(addr, __float_as_int(x)));
}

// ---------------- prep: squash + LN -> emb0 (fp32) + emb0b (bf16)
__global__ __launch_bounds__(256) void prep_kernel(
    const float* __restrict__ x, const float* __restrict__ g,
    const float* __restrict__ be, float* __restrict__ emb0,
    unsigned short* __restrict__ emb0b) {
  const int pos = blockIdx.x;
  const int t = threadIdx.x;
  float v = x[(size_t)pos * 256 + t];
  float sn = v * v;
  sn += __shfl_xor(sn, 1); sn += __shfl_xor(sn, 2);
  sn += __shfl_xor(sn, 4); sn += __shfl_xor(sn, 8);
  float e = v * (sn / (1.f + sn)) * rsqrtf(sn + 1e-9f);
  __shared__ float red[2][4];
  float s1 = e, s2 = e * e;
  for (int m = 1; m < 64; m <<= 1) { s1 += __shfl_xor(s1, m); s2 += __shfl_xor(s2, m); }
  if ((t & 63) == 0) { red[0][t >> 6] = s1; red[1][t >> 6] = s2; }
  __syncthreads();
  float tot = 0.f, tot2 = 0.f;
#pragma unroll
  for (int i = 0; i < 4; i++) { tot += red[0][i]; tot2 += red[1][i]; }
  float mean = tot * (1.f / 256.f);
  float var = tot2 * (1.f / 256.f) - mean * mean;
  float val = g[t] * (e - mean) * rsqrtf(var + 1e-3f) + be[t];
  emb0[(size_t)pos * 256 + t] = val;
  emb0b[(size_t)pos * 256 + t] = f2bf(val);
}

// ---------------- Bt builder: Bt[od][k] = W[(w*IN_H+h)][od*16+l], k=w*ESTR+h*16+l
template <int K, int ESTR, int IN_H>
__global__ __launch_bounds__(256) void conv_bt(
    const float* __restrict__ W, unsigned short* __restrict__ Bt) {
  int idx = blockIdx.x * 256 + threadIdx.x;
  if (idx >= 512 * K) return;
  int od = idx / K, k = idx - od * K;
  int w = k / ESTR, hl = k - w * ESTR;
  int h = hl >> 4, l = hl & 15;
  Bt[idx] = f2bf(W[(size_t)(w * IN_H + h) * 8192 + od * 16 + l]);
}

// ---------------- bias sum: bias[od] = sum_i Bi[i][od]
template <int INH>
__global__ __launch_bounds__(512) void bias_sum(
    const float* __restrict__ Bi, float* __restrict__ bias) {
  const int t = threadIdx.x;
  float s = 0.f;
  for (int i = 0; i < INH; i++) s += Bi[(size_t)i * 512 + t];
  bias[t] = s;
}

// ---------------- sa_gemm v2: barrier-free, LDS-free. Wave = 16p x 16od
// tile; lane loads its 16B A-fragment DIRECTLY from global embB (k-octets
// never cross window boundaries since ESTR%8==0) and B-fragment from Bt.
// All operands L2/L3-hot. Grid 64x8 blocks x 4 waves = 2048 independent
// waves (8/CU) -- r14's version was 1 block/CU with 2 barriers per K-step
// (63us, MfmaUtil 1.5%); this removes every barrier and every LDS access.
// Fragment index math identical to r14's HW-verified kernel.
template <int K, int ESTR>
__global__ __launch_bounds__(256) void sa_gemm(
    const unsigned short* __restrict__ embB, const unsigned short* __restrict__ Bt,
    const float* __restrict__ bias, float* __restrict__ sA) {
  const int pt = blockIdx.x;      // 16 positions per tile
  const int og = blockIdx.y;      // 8 od-groups of 64
  const int t = threadIdx.x;      // 256
  const int wv = t >> 6, l = t & 63;
  const int od0 = og * 64 + wv * 16;
  const int fr = l & 15;          // A-row (p) / B-row (od) / out col (od)
  const int koct = (l >> 4) * 8;  // k-octet offset within 32-chunk
  const int pg = pt * 16 + fr;
  const int sbase = pg & 255;
  const unsigned short* bptr = Bt + (size_t)(od0 + fr) * K + koct;
  f32x4 acc = {0.f, 0.f, 0.f, 0.f};
#pragma unroll 4
  for (int k0 = 0; k0 < K; k0 += 32) {
    const int k = k0 + koct;
    const int w = k / ESTR;            // ESTR pow2 -> shift
    const int c = k - w * ESTR;
    const int s = sbase + w - 2;
    bf16x8 af = {0, 0, 0, 0, 0, 0, 0, 0};
    if (s >= 0 && s < SEQ)
      af = *(const bf16x8*)(embB + (size_t)(pg + w - 2) * ESTR + c);
    bf16x8 bf = *(const bf16x8*)(bptr + k0);
    acc = __builtin_amdgcn_mfma_f32_16x16x32_bf16(af, bf, acc, 0, 0, 0);
  }
  const float bs = bias[od0 + fr];
#pragma unroll
  for (int j = 0; j < 4; j++) {
    int r = (l >> 4) * 4 + j;
    sA[(size_t)(pt * 16 + r) * 512 + od0 + fr] = acc[j] + bs;
  }
}

// ---------------- einsum (r12 PT=64 version, half2 stores)
template <int INH, int IN_H, int ESTR>
__global__ __launch_bounds__(512) void einsum_kernel(
    const float* __restrict__ W, const float* __restrict__ Bi,
    const float* __restrict__ emb, __half* __restrict__ u, int pos0) {
  constexpr int PT = 64;
  const int i = blockIdx.x;
  const int pt = blockIdx.y;
  const int t = threadIdx.x;
  const int c = t & 255;
  const int ph = t >> 8;
  const int w = i / IN_H, h = i % IN_H;
  __shared__ float W_lds[16][512];
  __shared__ float we_lds[PT][16];
  const float* Wi = W + (size_t)i * 8192;
#pragma unroll
  for (int j = 0; j < 4; j++) {
    const float4 wv = *(const float4*)(Wi + (size_t)t * 16 + j * 4);
    W_lds[j * 4 + 0][t] = wv.x; W_lds[j * 4 + 1][t] = wv.y;
    W_lds[j * 4 + 2][t] = wv.z; W_lds[j * 4 + 3][t] = wv.w;
  }
#pragma unroll
  for (int j = 0; j < PT * 16 / 512; j++) {
    int idx = t + j * 512;
    int p = idx >> 4, l = idx & 15;
    int pos = pos0 + pt * PT + p;
    int s = pos & 255;
    int sr = s + w - 2;
    float val = 0.f;
    if (sr >= 0 && sr < SEQ) val = emb[(size_t)(pos + (w - 2)) * ESTR + h * 16 + l];
    we_lds[p][l] = val;
  }
  __syncthreads();
  float wr0[16], wr1[16];
#pragma unroll
  for (int l = 0; l < 16; l++) { wr0[l] = W_lds[l][2 * c]; wr1[l] = W_lds[l][2 * c + 1]; }
  const float b0 = Bi[(size_t)i * 512 + 2 * c];
  const float b1 = Bi[(size_t)i * 512 + 2 * c + 1];
  __half* ub = u + ((size_t)(pt * PT + ph * 32) * INH + i) * 512 + 2 * c;
#pragma unroll 4
  for (int p2 = 0; p2 < 32; p2++) {
    const int p = ph * 32 + p2;
    float a0 = b0, a1 = b1;
#pragma unroll
    for (int l = 0; l < 16; l++) {
      float e = we_lds[p][l];
      a0 = fmaf(wr0[l], e, a0);
      a1 = fmaf(wr1[l], e, a1);
    }
    *(__half2*)(ub + (size_t)p2 * INH * 512) = __floats2half2_rn(a0, a1);
  }
}

// ---------------- routing: pass A read eliminated (sA precomputed via MFMA;
// v1 only feeds softmax logits -> bf16-grade sA safe, verified r14).
// u_hat streamed only 2x. DPP softmax; VGPR<=64 class.
template <int INH, bool MASK, bool FINAL>
__global__ __launch_bounds__(512) void route_kernel(
    const __half* __restrict__ u, const float* __restrict__ sA,
    const float* __restrict__ g, const float* __restrict__ be,
    const float* __restrict__ g_o, const float* __restrict__ b_o,
    float* __restrict__ outp, unsigned short* __restrict__ outb, int pos0) {
  constexpr int ROWS = INH / 8;
  const int w = threadIdx.x >> 6;
  const int l = threadIdx.x & 63;
  const int o = l >> 1;
  const int p = blockIdx.x;
  const int posg = pos0 + p;
  const int xaddr = ((l ^ 32) << 2);
  const __half* ug = u + (size_t)p * INH * 512 + (size_t)w * ROWS * 512 + l * 8;

  __shared__ float red_s[8][512];

#define UNPACK(q, f)                                            \
  {                                                             \
    float2 f0 = __half22float2(*(const __half2*)&(q).x);        \
    float2 f1 = __half22float2(*(const __half2*)&(q).y);        \
    float2 f2 = __half22float2(*(const __half2*)&(q).z);        \
    float2 f3 = __half22float2(*(const __half2*)&(q).w);        \
    f[0] = f0.x; f[1] = f0.y; f[2] = f1.x; f[3] = f1.y;         \
    f[4] = f2.x; f[5] = f2.y; f[6] = f3.x; f[7] = f3.y;         \
  }

  // ---- iter 1 from precomputed sA (2KB/position, L2-hot)
  float s8[8];
  {
    const float* sp = sA + (size_t)posg * 512 + l * 8;
    float4 a = *(const float4*)sp;
    float4 b = *(const float4*)(sp + 4);
    s8[0] = a.x; s8[1] = a.y; s8[2] = a.z; s8[3] = a.w;
    s8[4] = b.x; s8[5] = b.y; s8[6] = b.z; s8[7] = b.w;
  }
  const float c1 = MASK ? (o == 0 ? 0.f : (1.f / 31.f)) : (1.f / 32.f);
  float vd[8], vout[8];
  {
    float sn = 0.f;
#pragma unroll
    for (int k = 0; k < 8; k++) { s8[k] *= c1; sn += s8[k] * s8[k]; }
    sn = dpp_add<DPP_XOR1>(sn);
    float f = (sn / (1.f + sn)) * rsqrtf(sn + 1e-9f);
#pragma unroll
    for (int k = 0; k < 8; k++) vd[k] = s8[k] * f;  // vd = v1
  }

  // ---- passes B, C (iters 2, 3); pass C dots against v1+v2 (b telescopes)
#pragma unroll
  for (int iter = 0; iter < 2; iter++) {
    float sacc[8];
#pragma unroll
    for (int k = 0; k < 8; k++) sacc[k] = 0.f;
#pragma unroll 2
    for (int r = 0; r < ROWS; r++) {
      uint4 q = *(const uint4*)(ug + (size_t)r * 512);
      float u8[8];
      UNPACK(q, u8);
      float a = u8[0] * vd[0];
#pragma unroll
      for (int k = 1; k < 8; k++) a = fmaf(u8[k], vd[k], a);
      a = dpp_add<DPP_XOR1>(a);
      float e = (MASK && o == 0) ? 0.f : __expf(a);
      float ss = dpp_add<DPP_XOR1>(e);
      ss = dpp_add<DPP_XOR2>(ss);
      ss = dpp_add<DPP_ROR4>(ss);
      ss = dpp_add<DPP_ROR8>(ss);
      ss += swz_xor16(ss);
      ss += bperm(xaddr, ss);
      float c = __fdividef(e + e, ss);
#pragma unroll
      for (int k = 0; k < 8; k++) sacc[k] = fmaf(c, u8[k], sacc[k]);
    }
    __syncthreads();
    *(float4*)&red_s[w][l * 8]     = make_float4(sacc[0], sacc[1], sacc[2], sacc[3]);
    *(float4*)&red_s[w][l * 8 + 4] = make_float4(sacc[4], sacc[5], sacc[6], sacc[7]);
    __syncthreads();
#pragma unroll
    for (int k = 0; k < 8; k++) sacc[k] = 0.f;
#pragma unroll
    for (int w2 = 0; w2 < 8; w2++) {
      float4 a = *(const float4*)&red_s[w2][l * 8];
      float4 b = *(const float4*)&red_s[w2][l * 8 + 4];
      sacc[0] += a.x; sacc[1] += a.y; sacc[2] += a.z; sacc[3] += a.w;
      sacc[4] += b.x; sacc[5] += b.y; sacc[6] += b.z; sacc[7] += b.w;
    }
    float sn = 0.f;
#pragma unroll
    for (int k = 0; k < 8; k++) sn += sacc[k] * sacc[k];
    sn = dpp_add<DPP_XOR1>(sn);
    float f = (sn / (1.f + sn)) * rsqrtf(sn + 1e-9f);
#pragma unroll
    for (int k = 0; k < 8; k++) {
      vout[k] = sacc[k] * f;
      vd[k] += vout[k];
    }
  }

  // ---- epilogue: LN over 512
  float s1 = 0.f, s2 = 0.f;
#pragma unroll
  for (int k = 0; k < 8; k++) { s1 += vout[k]; s2 += vout[k] * vout[k]; }
  for (int m = 1; m < 64; m <<= 1) { s1 += __shfl_xor(s1, m); s2 += __shfl_xor(s2, m); }
  float mean = s1 * (1.f / 512.f);
  float var = s2 * (1.f / 512.f) - mean * mean;
  float rstd = rsqrtf(var + 1e-3f);
  const float4 g0 = *(const float4*)(g + 8 * l);
  const float4 g1 = *(const float4*)(g + 8 * l + 4);
  const float4 be0 = *(const float4*)(be + 8 * l);
  const float4 be1 = *(const float4*)(be + 8 * l + 4);
  float nv[8];
  nv[0] = g0.x * (vout[0] - mean) * rstd + be0.x;
  nv[1] = g0.y * (vout[1] - mean) * rstd + be0.y;
  nv[2] = g0.z * (vout[2] - mean) * rstd + be0.z;
  nv[3] = g0.w * (vout[3] - mean) * rstd + be0.w;
  nv[4] = g1.x * (vout[4] - mean) * rstd + be1.x;
  nv[5] = g1.y * (vout[5] - mean) * rstd + be1.y;
  nv[6] = g1.z * (vout[6] - mean) * rstd + be1.z;
  nv[7] = g1.w * (vout[7] - mean) * rstd + be1.w;

  if (!FINAL) {
    if (w == 0) {
      float4 w0 = {nv[0], nv[1], nv[2], nv[3]};
      float4 w1 = {nv[4], nv[5], nv[6], nv[7]};
      float* op = outp + (size_t)posg * 512 + 8 * l;
      *(float4*)op = w0; *(float4*)(op + 4) = w1;
      uint4 bb;
      bb.x = (unsigned)f2bf(nv[0]) | ((unsigned)f2bf(nv[1]) << 16);
      bb.y = (unsigned)f2bf(nv[2]) | ((unsigned)f2bf(nv[3]) << 16);
      bb.z = (unsigned)f2bf(nv[4]) | ((unsigned)f2bf(nv[5]) << 16);
      bb.w = (unsigned)f2bf(nv[6]) | ((unsigned)f2bf(nv[7]) << 16);
      *(uint4*)(outb + (size_t)posg * 512 + 8 * l) = bb;
    }
  } else {
    float l2 = 0.f;
#pragma unroll
    for (int k = 0; k < 8; k++) l2 += nv[k] * nv[k];
    l2 = dpp_add<DPP_XOR1>(l2);
    float len = sqrtf(l2 + 1e-9f);
    float a1 = len, a2 = len * len;
    for (int m = 1; m < 64; m <<= 1) { a1 += __shfl_xor(a1, m); a2 += __shfl_xor(a2, m); }
    float mm = a1 * (1.f / 64.f);
    float vv = a2 * (1.f / 64.f) - mm * mm;
    if (w == 0 && (l & 1) == 0)
      outp[(size_t)posg * 32 + o] = g_o[o] * (len - mm) * rsqrtf(vv + 1e-3f) + b_o[o];
  }
#undef UNPACK
}

extern "C" void kernel_launch(void* const* d_in, const int* in_sizes, int n_in,
                              void* d_out, int out_size, void* d_ws, size_t ws_size,
                              hipStream_t stream) {
  const float* x    = (const float*)d_in[0];
  const float* W0   = (const float*)d_in[1];
  const float* B0   = (const float*)d_in[2];
  const float* W1   = (const float*)d_in[3];
  const float* B1   = (const float*)d_in[4];
  const float* g_i  = (const float*)d_in[5];
  const float* b_i  = (const float*)d_in[6];
  const float* g_m0 = (const float*)d_in[7];
  const float* b_m0 = (const float*)d_in[8];
  const float* g_m1 = (const float*)d_in[9];
  const float* b_m1 = (const float*)d_in[10];
  const float* g_o  = (const float*)d_in[11];
  const float* b_o  = (const float*)d_in[12];
  float* out = (float*)d_out;

  char* ws = (char*)d_ws;
  float* emb0            = (float*)(ws);                      // 1 MB
  float* emb1            = (float*)(ws + 1048576);            // 2 MB
  unsigned short* emb0b  = (unsigned short*)(ws + 3145728);   // 0.5 MB
  unsigned short* emb1b  = (unsigned short*)(ws + 3670016);   // 1 MB
  float* sA0             = (float*)(ws + 4718592);            // 2 MB
  float* sA1             = (float*)(ws + 6815744);            // 2 MB
  unsigned short* Bt0    = (unsigned short*)(ws + 8912896);   // 1.25 MB
  unsigned short* Bt1    = (unsigned short*)(ws + 10223616);  // 2.5 MB
  float* bias0           = (float*)(ws + 12845056);           // 2 KB
  float* bias1           = (float*)(ws + 12849152);           // 2 KB
  __half* ubuf           = (__half*)(ws + 13107200);

  size_t avail = ws_size > (size_t)13107200 ? ws_size - 13107200 : 0;
  int chunk = 1024;
  while (chunk > 128 && (size_t)chunk * 163840 > avail) chunk >>= 1;

  prep_kernel<<<NPOS, 256, 0, stream>>>(x, g_i, b_i, emb0, emb0b);
  conv_bt<1280, 256, 16><<<(512 * 1280 + 255) / 256, 256, 0, stream>>>(W0, Bt0);
  conv_bt<2560, 512, 32><<<(512 * 2560 + 255) / 256, 256, 0, stream>>>(W1, Bt1);
  bias_sum<80><<<1, 512, 0, stream>>>(B0, bias0);
  bias_sum<160><<<1, 512, 0, stream>>>(B1, bias1);
  sa_gemm<1280, 256><<<dim3(64, 8), 256, 0, stream>>>(emb0b, Bt0, bias0, sA0);

  for (int p0 = 0; p0 < NPOS; p0 += chunk) {
    int cp = (NPOS - p0 < chunk) ? (NPOS - p0) : chunk;
    einsum_kernel<80, 16, 256><<<dim3(80, cp / 64), 512, 0, stream>>>(W0, B0, emb0, ubuf, p0);
    route_kernel<80, false, false><<<cp, 512, 0, stream>>>(ubuf, sA0, g_m0, b_m0, nullptr, nullptr, emb1, emb1b, p0);
  }

  sa_gemm<2560, 512><<<dim3(64, 8), 256, 0, stream>>>(emb1b, Bt1, bias1, sA1);

  for (int p0 = 0; p0 < NPOS; p0 += chunk) {
    int cp = (NPOS - p0 < chunk) ? (NPOS - p0) : chunk;
    einsum_kernel<160, 32, 512><<<dim3(160, cp / 64), 512, 0, stream>>>(W1, B1, emb1, ubuf, p0);
    route_kernel<160, true, true><<<cp, 512, 0, stream>>>(ubuf, sA1, g_m1, b_m1, g_o, b_o, out, nullptr, p0);
  }
}